// Round 10
// baseline (411.796 us; speedup 1.0000x reference)
//
#include <hip/hip_runtime.h>
#include <hip/hip_bf16.h>

#define TPB 256

typedef short s8v __attribute__((ext_vector_type(8)));     // 8 bf16 in 4 VGPRs
typedef float f4v __attribute__((ext_vector_type(4)));
typedef _Float16 h8v __attribute__((ext_vector_type(8)));  // 8 fp16 in 4 VGPRs

#define PB 256         // buckets
#define BSHIFT 9
#define BSPAN 512      // nodes per bucket
#define PCHUNK 4096    // edges per partition block
#define WBLK 192       // wsplit blocks (3*16384/256)
#define SRCMASK 0x1FFFF  // 17 bits (n < 131072)

// ---- fp32 -> bf16 split helpers (RNE) ----
__device__ __forceinline__ unsigned short bf16_rne(float v) {
    unsigned int u = __float_as_uint(v);
    u += 0x7fffu + ((u >> 16) & 1u);
    return (unsigned short)(u >> 16);
}
__device__ __forceinline__ void split_bf16(float v, unsigned short& hi, unsigned short& lo) {
    hi = bf16_rne(v);
    float hf = __uint_as_float((unsigned int)hi << 16);
    lo = bf16_rne(v - hf);
}

// ---------------- bhist + wsplit (merged) ----------------

__global__ __launch_bounds__(256) void bhist_wsplit_kernel(const int* __restrict__ dst, int E,
                                                           int* __restrict__ bsize,
                                                           const float* __restrict__ W0,
                                                           const float* __restrict__ W1,
                                                           const float* __restrict__ W2,
                                                           unsigned short* __restrict__ Whi,
                                                           unsigned short* __restrict__ Wlo) {
    __shared__ int h[PB];
    int t = threadIdx.x;
    if (blockIdx.x < WBLK) {
        int idx0 = blockIdx.x * 256 + t;            // 0 .. 3*16384
        if (idx0 < 3 * 16384) {
            int layer = idx0 >> 14;
            int e = idx0 & 16383;
            int k = e >> 7, ncol = e & 127;
            const float* W = (layer == 0) ? W0 : (layer == 1) ? W1 : W2;
            unsigned short hi, lo;
            split_bf16(W[e], hi, lo);
            int ct = ncol >> 4;
            int lane = (((k >> 3) & 3) << 4) | (ncol & 15);
            int kki = k >> 5;
            int j = k & 7;
            int oidx = layer * 16384 + (((ct * 4 + kki) * 64 + lane) * 8 + j);
            Whi[oidx] = hi; Wlo[oidx] = lo;
        }
        return;
    }
    int blk = blockIdx.x - WBLK;
    int nblk = gridDim.x - WBLK;
    h[t] = 0;
    __syncthreads();
    for (int e = blk * 256 + t; e < E; e += nblk * 256)
        atomicAdd(&h[dst[e] >> BSHIFT], 1);
    __syncthreads();
    if (h[t] > 0) atomicAdd(&bsize[t], h[t]);
}

// 256-thread exclusive scan of bucket sizes
__global__ void bscan_kernel(const int* __restrict__ bsize, int* __restrict__ bbase,
                             int* __restrict__ bcursor, int* __restrict__ row, int n, int E) {
    __shared__ int wtot[4];
    int t = threadIdx.x;            // 0..255
    int sz = bsize[t];
    int lane = t & 63, wid = t >> 6;
    int v = sz;
    for (int off = 1; off < 64; off <<= 1) {
        int u = __shfl_up(v, off);
        if (lane >= off) v += u;
    }
    if (lane == 63) wtot[wid] = v;
    __syncthreads();
    if (wid == 1) v += wtot[0];
    else if (wid == 2) v += wtot[0] + wtot[1];
    else if (wid == 3) v += wtot[0] + wtot[1] + wtot[2];
    bbase[t + 1] = v;               // inclusive
    bcursor[t] = v - sz;            // exclusive
    if (t == 0) { bbase[0] = 0; row[n] = E; }
}

// partition edges into bucket-contiguous packed ints: src | (localdst << 17)
__global__ __launch_bounds__(256) void partition_kernel(const int* __restrict__ src,
                                                        const int* __restrict__ dst, int E,
                                                        int* __restrict__ bcursor,
                                                        int* __restrict__ part) {
    __shared__ int h[PB];
    __shared__ int gofs[PB];
    int t = threadIdx.x;
    long base = (long)blockIdx.x * PCHUNK;
    int cnt = (int)min((long)PCHUNK, (long)E - base);

    h[t] = 0;
    __syncthreads();
    for (int j = t; j < cnt; j += 256)
        atomicAdd(&h[dst[base + j] >> BSHIFT], 1);
    __syncthreads();
    gofs[t] = (h[t] > 0) ? atomicAdd(&bcursor[t], h[t]) : 0;
    __syncthreads();
    h[t] = 0;           // reuse as local cursor
    __syncthreads();
    for (int j = t; j < cnt; j += 256) {
        int s = src[base + j], d = dst[base + j];   // re-read: L2-hot
        int b = d >> BSHIFT;
        int idx = atomicAdd(&h[b], 1);
        part[(long)gofs[b] + idx] = s | ((d & (BSPAN - 1)) << 17);
    }
}

// per-bucket degree histogram + scan -> row, dinv; bucket-local scatter -> esrc
__global__ __launch_bounds__(512) void csr_kernel(const int* __restrict__ part,
                                                  const int* __restrict__ bbase,
                                                  int* __restrict__ row, float* __restrict__ dinv,
                                                  int* __restrict__ esrc, int n) {
    __shared__ int deg[BSPAN];
    __shared__ int lrow[BSPAN];
    __shared__ int cur[BSPAN];
    __shared__ int wsum[8];
    int b = blockIdx.x;
    int n0 = b << BSHIFT;
    int nn = min(BSPAN, n - n0);
    if (nn <= 0) return;
    int e0 = bbase[b], e1 = bbase[b + 1];
    int t = threadIdx.x;

    deg[t] = 0;
    __syncthreads();
    for (int e = e0 + t; e < e1; e += 512)
        atomicAdd(&deg[((unsigned)part[e]) >> 17], 1);
    __syncthreads();

    int a = deg[t];
    int lane = t & 63, wid = t >> 6;
    int v = a;
    for (int off = 1; off < 64; off <<= 1) {
        int u = __shfl_up(v, off);
        if (lane >= off) v += u;
    }
    if (lane == 63) wsum[wid] = v;
    __syncthreads();
    if (wid == 0 && lane < 8) {
        int w = wsum[lane];
        for (int off = 1; off < 8; off <<= 1) {
            int u = __shfl_up(w, off);
            if (lane >= off) w += u;
        }
        wsum[lane] = w;
    }
    __syncthreads();
    int excl = v - a + ((wid > 0) ? wsum[wid - 1] : 0);
    lrow[t] = excl;
    cur[t] = 0;
    if (t < nn) {
        row[n0 + t] = e0 + excl;
        dinv[n0 + t] = rsqrtf((float)(deg[t] + 1));
    }
    __syncthreads();

    for (int e = e0 + t; e < e1; e += 512) {
        int p = part[e];
        int d = ((unsigned)p) >> 17;
        int idx = atomicAdd(&cur[d], 1);
        esrc[e0 + lrow[d] + idx] = p & SRCMASK;
    }
}

// ---------------- layer-0 GEMM: h0 = x @ W0 (fp16 out) ----------------

__global__ __launch_bounds__(256, 3) void gemm0_mfma(const float* __restrict__ Xf,
                                                     const unsigned short* __restrict__ Whs,
                                                     const unsigned short* __restrict__ Wls,
                                                     _Float16* __restrict__ Ch, int n) {
    __shared__ _Float16 Oh[128 * 136];
    int t = threadIdx.x;
    int wave = t >> 6, lane = t & 63;
    int ch = wave & 1, rh = wave >> 1;
    int lm = lane & 15, q = lane >> 4;
    long row0 = (long)blockIdx.x * 128 + rh * 64;

    const s8v* Wh8 = (const s8v*)Whs;
    const s8v* Wl8 = (const s8v*)Wls;

    f4v acc[4][4];
#pragma unroll
    for (int rt = 0; rt < 4; rt++)
#pragma unroll
        for (int ct = 0; ct < 4; ct++) acc[rt][ct] = (f4v)0.0f;

#pragma unroll
    for (int kki = 0; kki < 4; kki++) {
        s8v bh[4], bl[4];
#pragma unroll
        for (int ct = 0; ct < 4; ct++) {
            int idx = (((ch * 4 + ct) * 4 + kki) * 64) + lane;
            bh[ct] = Wh8[idx];
            bl[ct] = Wl8[idx];
        }
        s8v ah[4], al[4];
#pragma unroll
        for (int rt = 0; rt < 4; rt++) {
            long r = row0 + rt * 16 + lm;
            long rr = (r < n) ? r : (n - 1);   // clamp: padded rows discarded
            const float4* xf4 = (const float4*)(Xf + rr * 128 + kki * 32 + q * 8);
            float4 u0 = xf4[0], u1 = xf4[1];
            float uf[8] = {u0.x, u0.y, u0.z, u0.w, u1.x, u1.y, u1.z, u1.w};
            s8v hv, lv;
#pragma unroll
            for (int j = 0; j < 8; j++) {
                unsigned short hh, ll;
                split_bf16(uf[j], hh, ll);
                hv[j] = (short)hh; lv[j] = (short)ll;
            }
            ah[rt] = hv; al[rt] = lv;
        }
#pragma unroll
        for (int rt = 0; rt < 4; rt++)
#pragma unroll
            for (int ct = 0; ct < 4; ct++) {
                acc[rt][ct] = __builtin_amdgcn_mfma_f32_16x16x32_bf16(ah[rt], bh[ct], acc[rt][ct], 0, 0, 0);
                acc[rt][ct] = __builtin_amdgcn_mfma_f32_16x16x32_bf16(ah[rt], bl[ct], acc[rt][ct], 0, 0, 0);
                acc[rt][ct] = __builtin_amdgcn_mfma_f32_16x16x32_bf16(al[rt], bh[ct], acc[rt][ct], 0, 0, 0);
            }
    }

#pragma unroll
    for (int rt = 0; rt < 4; rt++)
#pragma unroll
        for (int reg = 0; reg < 4; reg++) {
            int lr = rh * 64 + rt * 16 + q * 4 + reg;
#pragma unroll
            for (int ct = 0; ct < 4; ct++)
                Oh[lr * 136 + ch * 64 + ct * 16 + lm] = (_Float16)acc[rt][ct][reg];
        }
    __syncthreads();

    long rowb = (long)blockIdx.x * 128;
    int lr = t >> 1;
    int cb = (t & 1) * 64;
    if (rowb + lr < n) {
        const uint4* s = (const uint4*)&Oh[lr * 136 + cb];
        uint4* d = (uint4*)&Ch[(rowb + lr) * 128 + cb];
#pragma unroll
        for (int u = 0; u < 8; u++) d[u] = s[u];
    }
}

// ---------------- gather core: 32 groups of 16 lanes, 2 groups per node ----------------
// acc[8] accumulates the half edge-range for node i (group pair g2: halves 0/1).

__device__ __forceinline__ void gather_half(const h8v* __restrict__ hIn,
                                            const float* __restrict__ dinv,
                                            const int* __restrict__ row,
                                            const int* __restrict__ esrc,
                                            long i, float di, int half, int lane,
                                            float acc[8]) {
    int e0 = row[i], e1 = row[i + 1];
    int mid = e0 + ((e1 - e0) >> 1);
    int es = half ? mid : e0;
    int ee = half ? e1 : mid;
    int e = es;
    for (; e + 4 <= ee; e += 4) {
        int s0 = esrc[e + 0];
        int s1 = esrc[e + 1];
        int s2i = esrc[e + 2];
        int s3 = esrc[e + 3];
        h8v v0 = hIn[(size_t)s0 * 16 + lane];
        h8v v1 = hIn[(size_t)s1 * 16 + lane];
        h8v v2 = hIn[(size_t)s2i * 16 + lane];
        h8v v3 = hIn[(size_t)s3 * 16 + lane];
        float w0 = dinv[s0] * di;
        float w1 = dinv[s1] * di;
        float w2 = dinv[s2i] * di;
        float w3 = dinv[s3] * di;
#pragma unroll
        for (int k = 0; k < 8; k++)
            acc[k] += w0 * (float)v0[k] + w1 * (float)v1[k] + w2 * (float)v2[k] + w3 * (float)v3[k];
    }
    for (; e < ee; ++e) {
        int s = esrc[e];
        h8v v = hIn[(size_t)s * 16 + lane];
        float w = dinv[s] * di;
#pragma unroll
        for (int k = 0; k < 8; k++) acc[k] += w * (float)v[k];
    }
}

// ---------------- fused agg + next-layer GEMM (512 threads, 16 nodes) ----------------

__global__ __launch_bounds__(512) void fused_kernel(const h8v* __restrict__ hIn,
                                                    const float* __restrict__ dinv,
                                                    const int* __restrict__ row,
                                                    const int* __restrict__ esrc,
                                                    const float* __restrict__ bias,
                                                    const unsigned short* __restrict__ Whs,
                                                    const unsigned short* __restrict__ Wls,
                                                    _Float16* __restrict__ hOut, int n) {
    __shared__ float As[16 * 132];   // relu'd rows; reused as fp16 out-stage (stride 136)
    __shared__ float Bs[16 * 132];   // odd-half partial sums
    int t = threadIdx.x;
    int grp = t >> 4, lane = t & 15;
    int g2 = grp >> 1, half = grp & 1;
    long i = (long)blockIdx.x * 16 + g2;

    float acc[8];
#pragma unroll
    for (int k = 0; k < 8; k++) acc[k] = 0.f;
    float di = 0.f;
    if (i < n) {
        di = dinv[i];
        gather_half(hIn, dinv, row, esrc, i, di, half, lane, acc);
    }
    if (half) {
        float* d = &Bs[g2 * 132 + lane * 8];
        *(float4*)d = make_float4(acc[0], acc[1], acc[2], acc[3]);
        *(float4*)(d + 4) = make_float4(acc[4], acc[5], acc[6], acc[7]);
    }
    __syncthreads();
    if (!half) {
        float r[8];
        const float* o = &Bs[g2 * 132 + lane * 8];
        float4 oa = *(const float4*)o, ob = *(const float4*)(o + 4);
        float oth[8] = {oa.x, oa.y, oa.z, oa.w, ob.x, ob.y, ob.z, ob.w};
        float s2 = di * di;
        const float4* b4 = (const float4*)(bias + lane * 8);
        float4 bA = b4[0], bB = b4[1];
        float bb[8] = {bA.x, bA.y, bA.z, bA.w, bB.x, bB.y, bB.z, bB.w};
        if (i < n) {
            h8v self = hIn[i * 16 + lane];
#pragma unroll
            for (int k = 0; k < 8; k++)
                r[k] = fmaxf(acc[k] + oth[k] + (float)self[k] * s2 + bb[k], 0.f);
        } else {
#pragma unroll
            for (int k = 0; k < 8; k++) r[k] = 0.f;
        }
        float* dstA = &As[g2 * 132 + lane * 8];
        *(float4*)dstA = make_float4(r[0], r[1], r[2], r[3]);
        *(float4*)(dstA + 4) = make_float4(r[4], r[5], r[6], r[7]);
    }
    __syncthreads();

    // GEMM: 8 waves, wave w handles col-tile ct = w (16 cols)
    int w = t >> 6, l64 = t & 63;
    int lm = l64 & 15, q = l64 >> 4;

    const s8v* Wh8 = (const s8v*)Whs;
    const s8v* Wl8 = (const s8v*)Wls;
    s8v Bh[4], Bl[4];
#pragma unroll
    for (int kki = 0; kki < 4; kki++) {
        int idx = ((w * 4 + kki) * 64) + l64;
        Bh[kki] = Wh8[idx];
        Bl[kki] = Wl8[idx];
    }

    f4v a2 = (f4v)0.0f;
#pragma unroll
    for (int kki = 0; kki < 4; kki++) {
        const float* ap = &As[lm * 132 + kki * 32 + q * 8];
        float4 u0 = *(const float4*)ap;
        float4 u1 = *(const float4*)(ap + 4);
        float uf[8] = {u0.x, u0.y, u0.z, u0.w, u1.x, u1.y, u1.z, u1.w};
        s8v hv, lv;
#pragma unroll
        for (int j = 0; j < 8; j++) {
            unsigned short hh, ll;
            split_bf16(uf[j], hh, ll);
            hv[j] = (short)hh; lv[j] = (short)ll;
        }
        a2 = __builtin_amdgcn_mfma_f32_16x16x32_bf16(hv, Bh[kki], a2, 0, 0, 0);
        a2 = __builtin_amdgcn_mfma_f32_16x16x32_bf16(hv, Bl[kki], a2, 0, 0, 0);
        a2 = __builtin_amdgcn_mfma_f32_16x16x32_bf16(lv, Bh[kki], a2, 0, 0, 0);
    }
    __syncthreads();

    _Float16* Oh = (_Float16*)As;    // 16 x 136 halves (272B rows, 16B-aligned)
#pragma unroll
    for (int reg = 0; reg < 4; reg++)
        Oh[(q * 4 + reg) * 136 + w * 16 + lm] = (_Float16)a2[reg];
    __syncthreads();

    if (t < 256) {
        long gi = (long)blockIdx.x * 16 + (t >> 4);
        if (gi < n) {
            uint4 v = *(const uint4*)&Oh[(t >> 4) * 136 + (t & 15) * 8];
            *(uint4*)&hOut[gi * 128 + (size_t)(t & 15) * 8] = v;
        }
    }
}

// ---------------- final aggregation (512 threads, fp32 out) ----------------

__global__ __launch_bounds__(512) void agg_final(const h8v* __restrict__ hH,
                                                 const float* __restrict__ dinv,
                                                 const int* __restrict__ row,
                                                 const int* __restrict__ esrc,
                                                 const float* __restrict__ bias,
                                                 float* __restrict__ out, int n) {
    __shared__ float Bs[16 * 132];
    int t = threadIdx.x;
    int grp = t >> 4, lane = t & 15;
    int g2 = grp >> 1, half = grp & 1;
    long i = (long)blockIdx.x * 16 + g2;

    float acc[8];
#pragma unroll
    for (int k = 0; k < 8; k++) acc[k] = 0.f;
    float di = 0.f;
    if (i < n) {
        di = dinv[i];
        gather_half(hH, dinv, row, esrc, i, di, half, lane, acc);
    }
    if (half) {
        float* d = &Bs[g2 * 132 + lane * 8];
        *(float4*)d = make_float4(acc[0], acc[1], acc[2], acc[3]);
        *(float4*)(d + 4) = make_float4(acc[4], acc[5], acc[6], acc[7]);
    }
    __syncthreads();
    if (!half && i < n) {
        const float* o = &Bs[g2 * 132 + lane * 8];
        float4 oa = *(const float4*)o, ob = *(const float4*)(o + 4);
        float oth[8] = {oa.x, oa.y, oa.z, oa.w, ob.x, ob.y, ob.z, ob.w};
        float s2 = di * di;
        h8v self = hH[i * 16 + lane];
        const float4* b4 = (const float4*)(bias + lane * 8);
        float4 bA = b4[0], bB = b4[1];
        float bb[8] = {bA.x, bA.y, bA.z, bA.w, bB.x, bB.y, bB.z, bB.w};
        float r[8];
#pragma unroll
        for (int k = 0; k < 8; k++)
            r[k] = fmaxf(acc[k] + oth[k] + (float)self[k] * s2 + bb[k], 0.f);
        float4* o4 = (float4*)(out + i * 128 + lane * 8);
        o4[0] = make_float4(r[0], r[1], r[2], r[3]);
        o4[1] = make_float4(r[4], r[5], r[6], r[7]);
    }
}

// ---------------- launch ----------------

extern "C" void kernel_launch(void* const* d_in, const int* in_sizes, int n_in,
                              void* d_out, int out_size, void* d_ws, size_t ws_size,
                              hipStream_t stream) {
    const float* x  = (const float*)d_in[0];
    const int*   ei = (const int*)d_in[1];
    const float* W0 = (const float*)d_in[2];
    const float* b0 = (const float*)d_in[3];
    const float* W1 = (const float*)d_in[4];
    const float* b1 = (const float*)d_in[5];
    const float* W2 = (const float*)d_in[6];
    const float* b2 = (const float*)d_in[7];

    const int H = 128;
    int n = in_sizes[0] / H;
    int E = in_sizes[1] / 2;
    const int* srcp = ei;
    const int* dstp = ei + E;

    int gemm_blocks = (n + 127) / 128;
    long npad = (long)gemm_blocks * 128;
    int nbuck = (n + BSPAN - 1) >> BSHIFT;   // 196 for n=100k, <= PB

    char* p = (char*)d_ws;
    auto alloc = [&](size_t bytes) {
        void* r = (void*)p;
        p += (bytes + 255) & ~(size_t)255;
        return r;
    };
    _Float16* bufH0 = (_Float16*)alloc((size_t)npad * H * 2);               // 25.6 MB
    _Float16* bufH1 = (_Float16*)alloc((size_t)npad * H * 2);               // 25.6 MB
    unsigned short* Whs = (unsigned short*)alloc(3 * 16384 * 2);
    unsigned short* Wls = (unsigned short*)alloc(3 * 16384 * 2);
    float* dinv  = (float*)alloc((size_t)n * sizeof(float));
    int*  row    = (int*)alloc((size_t)(n + 1) * sizeof(int));
    int*  bsize  = (int*)alloc(PB * sizeof(int));
    int*  bbase  = (int*)alloc((PB + 1) * sizeof(int));
    int*  bcursor= (int*)alloc(PB * sizeof(int));
    int*  part   = (int*)alloc((size_t)E * sizeof(int));                    // 6.4 MB packed
    int*  esrc   = (int*)alloc((size_t)E * sizeof(int));                    // 6.4 MB

    hipMemsetAsync(bsize, 0, PB * sizeof(int), stream);

    bhist_wsplit_kernel<<<WBLK + 1024, 256, 0, stream>>>(dstp, E, bsize, W0, W1, W2, Whs, Wls);
    bscan_kernel<<<1, PB, 0, stream>>>(bsize, bbase, bcursor, row, n, E);
    partition_kernel<<<(E + PCHUNK - 1) / PCHUNK, 256, 0, stream>>>(srcp, dstp, E, bcursor, part);
    csr_kernel<<<nbuck, 512, 0, stream>>>(part, bbase, row, dinv, esrc, n);

    float* out = (float*)d_out;
    int node_blocks = (n + 15) / 16;

    // layer 0 linear: x @ W0 -> bufH0 (fp16)
    gemm0_mfma<<<gemm_blocks, 256, 0, stream>>>(x, Whs, Wls, bufH0, n);
    // fused: relu(agg(bufH0)+b0) @ W1 -> bufH1
    fused_kernel<<<node_blocks, 512, 0, stream>>>((const h8v*)bufH0, dinv, row, esrc, b0,
                                                  Whs + 16384, Wls + 16384, bufH1, n);
    // fused: relu(agg(bufH1)+b1) @ W2 -> bufH0
    fused_kernel<<<node_blocks, 512, 0, stream>>>((const h8v*)bufH1, dinv, row, esrc, b1,
                                                  Whs + 32768, Wls + 32768, bufH0, n);
    // final: relu(agg(bufH0)+b2) -> out (fp32)
    agg_final<<<node_blocks, 512, 0, stream>>>((const h8v*)bufH0, dinv, row, esrc, b2, out, n);
}